// Round 7
// baseline (140.753 us; speedup 1.0000x reference)
//
#include <hip/hip_runtime.h>
#include <math.h>

// B=16384 rows, C=1000 cols, fp32 -> 16384 fp32.
//
// R10 = R9 (floor kernel, 44.3 us cold / 43.2 us warm) with ONE variable
// changed: the two payload loads are NON-TEMPORAL (nt flag). This is the
// final discriminating experiment for the read-path-ceiling model:
//
//   MODEL: fabric/L3 READ direction delivers ~3.15 TB/s (write path ~6.5):
//    * 131 MB / 43.5 us = 3.01 TB/s identical for HBM-cold AND L3-warm
//      (warm replays: hbm_bytes 0.5 MB, dur still 43 us) across THREE
//      structures (wave-per-row, block-per-row, persistent grid; R1-R9).
//    * m13 "6.29 TB/s copy" = read+write total -> 3.15 TB/s per direction.
//    * fillBufferAligned (write-only) = 6.5 TB/s in this same harness.
//    * Ruled out by arithmetic: TA issue rate (1 VMEM/203cy/CU), L1 fill,
//      VALU (17-43%), LDS, dispatch, occupancy, allocator/latency (R8 asm
//      batches with counted vmcnt changed nothing).
//
//   PRE-COMMITTED READ: nt null (43-46 us) => ceiling is the physical read
//   path; declare ROOFLINE. nt positive (<35 us) => fill-allocate policy
//   was the cap; keep optimizing.

constexpr int kC  = 1000;
constexpr int kNV = kC / 4;        // 250 float4 per row; threads 250..255 pad

typedef float f32x4 __attribute__((ext_vector_type(4)));

__global__ __launch_bounds__(256, 8) void netsat_kernel(
    const float* __restrict__ y1, const float* __restrict__ y2,
    float* __restrict__ out, int nrows)
{
    const int tid  = threadIdx.x;
    const int lane = tid & 63;
    const int wave = tid >> 6;
    const int row  = blockIdx.x;
    if (row >= nrows) return;

    const f32x4* r1 = reinterpret_cast<const f32x4*>(y1) + (size_t)row * kNV;
    const f32x4* r2 = reinterpret_cast<const f32x4*>(y2) + (size_t)row * kNV;

    // Unconditional clamped loads (branchless), mask pad threads after load.
    // NON-TEMPORAL: evict-first in L1/L2/L3 — streaming policy.
    const int vi = (tid < kNV) ? tid : (kNV - 1);
    f32x4 a = __builtin_nontemporal_load(&r1[vi]);
    f32x4 b = __builtin_nontemporal_load(&r2[vi]);
    if (tid >= kNV) {
        a = (f32x4){-INFINITY, -INFINITY, -INFINITY, -INFINITY};
        b = (f32x4){-INFINITY, -INFINITY, -INFINITY, -INFINITY};
    }

    // ---- local top-2 over this thread's 4 elements, both inputs ----
    float m1 = -INFINITY, m2 = -INFINITY;   // y1 top-2
    float n1 = -INFINITY, n2 = -INFINITY;   // y2 top-2
#pragma unroll
    for (int k = 0; k < 4; ++k) {
        const float v = a[k];
        m2 = fmaxf(m2, fminf(m1, v)); m1 = fmaxf(m1, v);
        const float w = b[k];
        n2 = fmaxf(n2, fminf(n1, w)); n1 = fmaxf(n1, w);
    }

    // ---- wave butterfly merge of (top1, top2); m/n chains interleave ----
#pragma unroll
    for (int off = 32; off > 0; off >>= 1) {
        const float o1 = __shfl_xor(m1, off, 64);
        const float o2 = __shfl_xor(m2, off, 64);
        const float p1 = __shfl_xor(n1, off, 64);
        const float p2 = __shfl_xor(n2, off, 64);
        m2 = fmaxf(fminf(m1, o1), fmaxf(m2, o2));
        m1 = fmaxf(m1, o1);
        n2 = fmaxf(fminf(n1, p1), fmaxf(n2, p2));
        n1 = fmaxf(n1, p1);
    }

    // ---- cross-wave merge via LDS; every thread merges all 4 wave results
    __shared__ float sm[4][4];     // [wave] = {m1, m2, n1, n2}
    __shared__ float sbest[4];
    if (lane == 0) {
        sm[wave][0] = m1; sm[wave][1] = m2;
        sm[wave][2] = n1; sm[wave][3] = n2;
    }
    __syncthreads();

    float M1 = -INFINITY, M2 = -INFINITY, N1 = -INFINITY, N2 = -INFINITY;
#pragma unroll
    for (int w = 0; w < 4; ++w) {
        const float w1 = sm[w][0], w2 = sm[w][1];
        M2 = fmaxf(fminf(M1, w1), fmaxf(M2, w2));
        M1 = fmaxf(M1, w1);
        const float u1 = sm[w][2], u2 = sm[w][3];
        N2 = fmaxf(fminf(N1, u1), fmaxf(N2, u2));
        N1 = fmaxf(N1, u1);
    }

    // ---- pass 2 over REGISTER payload: max_j min(v - loo1, w - loo2) ----
    // loo(v) = (v==M1) ? M2 : M1 — tie-safe (duplicated max => M2==M1).
    float best = -INFINITY;
#pragma unroll
    for (int k = 0; k < 4; ++k) {
        const float v = a[k];
        const float w = b[k];
        const float l1 = (v == M1) ? M2 : M1;
        const float l2 = (w == N1) ? N2 : N1;
        best = fmaxf(best, fminf(v - l1, w - l2));
    }
#pragma unroll
    for (int off = 32; off > 0; off >>= 1)
        best = fmaxf(best, __shfl_xor(best, off, 64));

    if (lane == 0) sbest[wave] = best;
    __syncthreads();

    if (tid == 0) {
        float r = fmaxf(fmaxf(sbest[0], sbest[1]), fmaxf(sbest[2], sbest[3]));
        out[row] = r;
    }
}

extern "C" void kernel_launch(void* const* d_in, const int* in_sizes, int n_in,
                              void* d_out, int out_size, void* d_ws, size_t ws_size,
                              hipStream_t stream) {
    const float* y1 = (const float*)d_in[0];
    const float* y2 = (const float*)d_in[1];
    float* out = (float*)d_out;
    const int nrows = out_size;  // 16384
    netsat_kernel<<<nrows, 256, 0, stream>>>(y1, y2, out, nrows);
}